// Round 5
// baseline (431.965 us; speedup 1.0000x reference)
//
#include <hip/hip_runtime.h>
#include <math.h>

// ---------------------------------------------------------------------------
// HimNet multimode v5. B=8,N=1000,CIN=16,H=64,D=16,K=3,XIN=80,K*XIN=240,2H=128
//
// cheb GEMMs feature-major: T1t[f][n] = sum_k Xt[f][k]*S16[n][k].
//   cheb_v5: block 64f x 128n, K chunked 256; A-chunk glds->LDS->regs;
//   S streamed global->registers (no LDS, no per-tile barrier).
// meta GEMM: A[8000x256] vs Btd d-major (Btd[(d*O+o)][k]=W[d,k,o]).
//   meta4: A resident (LDS->regs, staged once); B streamed global->regs;
//   zero barriers in tile loop; outacc += ew[n,d]*acc in registers.
// ---------------------------------------------------------------------------

typedef __attribute__((ext_vector_type(8))) short s16x8;
typedef __attribute__((ext_vector_type(4))) float f32x4;
typedef unsigned short u16;
typedef unsigned int u32;
typedef unsigned long long u64;

__device__ __forceinline__ u32 f2bf(float f) {
  union { float f; u32 u; } v; v.f = f;
  return (v.u + 0x7FFFu + ((v.u >> 16) & 1u)) >> 16;  // RNE
}
__device__ __forceinline__ float bf2f(u16 h) {
  union { u32 u; float f; } v; v.u = (u32)h << 16; return v.f;
}
__device__ __forceinline__ void glds16(const u16* g, u16* l) {
  __builtin_amdgcn_global_load_lds(
      (const __attribute__((address_space(1))) void*)g,
      (__attribute__((address_space(3))) void*)l, 16, 0, 0);
}

// ---------------------------------------------------------------------------
// prep: S16[3][1024][1024], Xt[3][640][1024], Ag kc0 slots, AgU x-slots,
// K-pads, n-pad rows of T1t/ZSt/SZ1t.
// ---------------------------------------------------------------------------
#define E0 3145728
#define E1 1966080
#define E2 1920000
#define E3 384000
#define E4 384000
#define E5 384000
#define E6 119808
// total = 8303616 = 32436 * 256

struct PrepArgs {
  const float* x[3]; const float* st[3]; const float* S[3];
  u16 *S16, *Xt, *Ag, *AgU, *T1t, *ZSt, *SZ1t;
};

__global__ void prep(PrepArgs P) {
  long idx = (long)blockIdx.x * 256 + threadIdx.x;
  if (idx < E0) {  // S16 incl pads
    int m = (int)(idx >> 20); int rem = (int)(idx & 1048575);
    int n = rem >> 10, k = rem & 1023;
    float v = (n < 1000 && k < 1000) ? P.S[m][n * 1000 + k] : 0.f;
    P.S16[(size_t)m * 1048576 + rem] = (u16)f2bf(v); return;
  }
  idx -= E0;
  if (idx < E1) {  // Xt incl n-pads
    int m = (int)(idx / 655360); int rem = (int)(idx % 655360);
    int col = rem >> 10, nn = rem & 1023;
    int b = col / 80, c = col % 80;
    float v = 0.f;
    if (nn < 1000) v = (c < 16) ? P.x[m][(b * 1000 + nn) * 16 + c]
                                : P.st[m][(b * 1000 + nn) * 64 + c - 16];
    P.Xt[(size_t)m * 655360 + rem] = (u16)f2bf(v); return;
  }
  idx -= E1;
  if (idx < E2) {  // Ag kc0 (cols 0..79)
    int m = (int)(idx / 640000); int rem = (int)(idx % 640000);
    int r = rem / 80, c = rem % 80;
    int n = r >> 3, b = r & 7;
    float v = (c < 16) ? P.x[m][(b * 1000 + n) * 16 + c]
                       : P.st[m][(b * 1000 + n) * 64 + c - 16];
    P.Ag[(size_t)m * 2048000 + (size_t)r * 256 + c] = (u16)f2bf(v); return;
  }
  idx -= E2;
  if (idx < E3) {  // Ag K-pad 240..255
    int m = (int)(idx / 128000); int rem = (int)(idx % 128000);
    int r = rem / 16, c = 240 + rem % 16;
    P.Ag[(size_t)m * 2048000 + (size_t)r * 256 + c] = 0; return;
  }
  idx -= E3;
  if (idx < E4) {  // AgU kc0 x-part (cols 0..15)
    int m = (int)(idx / 128000); int rem = (int)(idx % 128000);
    int r = rem / 16, c = rem % 16;
    int n = r >> 3, b = r & 7;
    P.AgU[(size_t)m * 2048000 + (size_t)r * 256 + c] =
        (u16)f2bf(P.x[m][(b * 1000 + n) * 16 + c]); return;
  }
  idx -= E4;
  if (idx < E5) {  // AgU K-pad
    int m = (int)(idx / 128000); int rem = (int)(idx % 128000);
    int r = rem / 16, c = 240 + rem % 16;
    P.AgU[(size_t)m * 2048000 + (size_t)r * 256 + c] = 0; return;
  }
  idx -= E5;
  if (idx < E6) {  // n-pad rows (k=1000..1023) of T1t/ZSt/SZ1t
    int m = (int)(idx / 39936); int rem = (int)(idx % 39936);
    if (rem < 15360) { int col = rem / 24, j = rem % 24;
      P.T1t[(size_t)m * 655360 + col * 1024 + 1000 + j] = 0; }
    else if (rem < 27648) { int e = rem - 15360; int col = e / 24, j = e % 24;
      P.ZSt[(size_t)m * 524288 + col * 1024 + 1000 + j] = 0; }
    else { int e = rem - 27648; int col = e / 24, j = e % 24;
      P.SZ1t[(size_t)m * 524288 + col * 1024 + 1000 + j] = 0; }
    return;
  }
}

// ---------------------------------------------------------------------------
// bias: outB[mode][n*O+o] = sum_d emb[n,d]*me[mode,d]*Bp[d,o]
// ---------------------------------------------------------------------------
__global__ void bias_kernel(const float* __restrict__ e0, const float* __restrict__ e1,
                            const float* __restrict__ e2, const float* __restrict__ me,
                            const float* __restrict__ Bp, int O, float* __restrict__ outB) {
  int idx = blockIdx.x * blockDim.x + threadIdx.x;
  int total = 3 * 1000 * O;
  if (idx >= total) return;
  int mode = idx / (1000 * O);
  int rem  = idx % (1000 * O);
  int n = rem / O, o = rem % O;
  const float* emb = (mode == 0) ? e0 : (mode == 1) ? e1 : e2;
  float s = 0.f;
#pragma unroll
  for (int d = 0; d < 16; ++d)
    s += emb[n * 16 + d] * me[mode * 16 + d] * Bp[d * O + o];
  outB[idx] = s;
}

// ---------------------------------------------------------------------------
// packW (d-major): Bt[(d*O+o)][k] = bf16(W[d,k,o]) k<240, else 0.
// ---------------------------------------------------------------------------
__global__ void packW_kernel(const float* __restrict__ Wg, const float* __restrict__ Wu,
                             u16* __restrict__ BtG, u16* __restrict__ BtU) {
  int idx = blockIdx.x * blockDim.x + threadIdx.x;
  if (idx >= (2048 + 1024) * 256) return;
  if (idx < 2048 * 256) {
    int col = idx >> 8, k = idx & 255;
    int d = col >> 7, o = col & 127;
    BtG[idx] = (k < 240) ? (u16)f2bf(Wg[d * 30720 + k * 128 + o]) : (u16)0;
  } else {
    int i2 = idx - 2048 * 256;
    int col = i2 >> 8, k = i2 & 255;
    int d = col >> 6, o = col & 63;
    BtU[i2] = (k < 240) ? (u16)f2bf(Wu[d * 15360 + k * 64 + o]) : (u16)0;
  }
}

// ---------------------------------------------------------------------------
// cheb_v5: D[f][n] = alpha*sum_k A[f][k]*S16[n][k] (+beta*Res[f][n])
// Block 64f x 128n, K chunked 256 (4 chunks). A-chunk glds->LDS, hoisted to
// regs; S streamed global->regs. 4 waves 2x2: wave = 32f x 64n.
// flags: 1=hasRes, 2=hasY, 4=hasAgX
// ---------------------------------------------------------------------------
struct ChebArgs2 {
  const u16* S16[3]; const u16* A[3]; const u16* Res[3];
  u16* Yt[3]; u16* AgA[3]; u16* AgX[3];
};

__global__ __launch_bounds__(256, 2) void cheb_v5(ChebArgs2 g, int fdiv, int agbase,
                                                  float alpha, float beta, int flags) {
  const int mode = blockIdx.z;
  const u16* __restrict__ Ab = g.A[mode];
  const u16* __restrict__ Sb = g.S16[mode];

  __shared__ u16 As[64 * 256];   // 32KB, swizzled chunks

  const int t = threadIdx.x;
  const int row0 = blockIdx.y * 64, n0 = blockIdx.x * 128;
  const int lane = t & 63, wid = t >> 6;
  const int l16 = lane & 15, quad = lane >> 4;
  const int wy = (wid >> 1) * 32, wx = (wid & 1) * 64;

  f32x4 acc[2][4];
#pragma unroll
  for (int a = 0; a < 2; ++a)
#pragma unroll
    for (int b = 0; b < 4; ++b) acc[a][b] = (f32x4){0.f, 0.f, 0.f, 0.f};

  // per-lane B base: row (n0+wx+ni*16+l16), k offset quad*8
  const u16* Bbase = Sb + (size_t)(n0 + wx + l16) * 1024 + quad * 8;

  for (int k0 = 0; k0 < 1024; k0 += 256) {
    // stage A chunk 64x256 = 2048 x 16B, 8 glds/thread
#pragma unroll
    for (int p = 0; p < 8; ++p) {
      int idx = p * 256 + t; int row = idx >> 5; int cs = (idx & 31) ^ (row & 7);
      glds16(Ab + (size_t)(row0 + row) * 1024 + k0 + cs * 8, &As[idx * 8]);
    }
    __syncthreads();
    s16x8 afr[2][8];
#pragma unroll
    for (int mi = 0; mi < 2; ++mi) {
      int row = wy + mi * 16 + l16;
#pragma unroll
      for (int ki = 0; ki < 8; ++ki) {
        int cl = (ki * 4 + quad) ^ (row & 7);
        afr[mi][ki] = *(const s16x8*)&As[row * 256 + cl * 8];
      }
    }
    __syncthreads();  // all hoists done before next chunk restages

#pragma unroll
    for (int ki = 0; ki < 8; ++ki) {
      s16x8 bfr[4];
#pragma unroll
      for (int ni = 0; ni < 4; ++ni)
        bfr[ni] = *(const s16x8*)(Bbase + (size_t)ni * 16 * 1024 + k0 + ki * 32);
#pragma unroll
      for (int mi = 0; mi < 2; ++mi)
#pragma unroll
        for (int ni = 0; ni < 4; ++ni)
          acc[mi][ni] = __builtin_amdgcn_mfma_f32_16x16x32_bf16(afr[mi][ki], bfr[ni], acc[mi][ni], 0, 0, 0);
    }
  }

#pragma unroll
  for (int mi = 0; mi < 2; ++mi) {
    int frow0 = row0 + wy + mi * 16 + quad * 4;
    int b = frow0 / fdiv, c0 = frow0 - b * fdiv;
#pragma unroll
    for (int ni = 0; ni < 4; ++ni) {
      int n = n0 + wx + ni * 16 + l16;
      if (n < 1000) {
        u16 pk[4];
#pragma unroll
        for (int r = 0; r < 4; ++r) {
          float v = alpha * acc[mi][ni][r];
          if (flags & 1) v += beta * bf2f(g.Res[mode][(size_t)(frow0 + r) * 1024 + n]);
          u16 h = (u16)f2bf(v);
          pk[r] = h;
          if (flags & 2) g.Yt[mode][(size_t)(frow0 + r) * 1024 + n] = h;
        }
        u64 pv = (u64)pk[0] | ((u64)pk[1] << 16) | ((u64)pk[2] << 32) | ((u64)pk[3] << 48);
        *(u64*)&g.AgA[mode][(size_t)(n * 8 + b) * 256 + agbase + c0] = pv;
        if ((flags & 4) && c0 < 16)
          *(u64*)&g.AgX[mode][(size_t)(n * 8 + b) * 256 + agbase + c0] = pv;
      }
    }
  }
}

// ---------------------------------------------------------------------------
// meta4: out[r,o] = act( sum_d ew[n,d]*(A[r,:].Btd[d*O+o,:]) + bias[n,o] )
// Block 64 rows; A staged once (glds->LDS->regs); B streamed global->regs;
// no barriers in tile loop. 4 waves 2x2: wave = 32 rows x 32 cols.
// ---------------------------------------------------------------------------
struct Meta3Args {
  const u16* Ag;        // [3][8000][256]
  const u16* Bt;        // [O*16][256] d-major
  const float* emb[3];
  const float* me;
  const float* Bias;    // [3][1000][O]
  const float* state[3];
  u16* ZSt;             // [3][512][1024]
  u16* AgU;             // [3][8000][256]
  float* Rb;            // [3][8000][64]
  float* out;
};

__global__ __launch_bounds__(256, 2) void meta4(Meta3Args A, int is_gate, int O) {
  const int mode = blockIdx.z;
  const int row0 = blockIdx.y * 64;
  const int n0 = row0 >> 3;

  __shared__ u16 As[64 * 256];   // 32KB, swizzled
  __shared__ float ewS[8][17];

  const int t = threadIdx.x;
  if (t < 128) {
    int nl = t >> 4, d = t & 15;
    ewS[nl][d] = A.emb[mode][(n0 + nl) * 16 + d] * A.me[mode * 16 + d];
  }

  const int lane = t & 63, wid = t >> 6;
  const int l16 = lane & 15, quad = lane >> 4;
  const int wy = (wid >> 1) * 32, wx = (wid & 1) * 32;
  const u16* Agm = A.Ag + (size_t)mode * 2048000;

  // stage A rows [row0,row0+64) x K256: 2048 x 16B, 8 glds/thread
#pragma unroll
  for (int p = 0; p < 8; ++p) {
    int idx = p * 256 + t; int row = idx >> 5; int cs = (idx & 31) ^ (row & 7);
    glds16(Agm + (size_t)(row0 + row) * 256 + cs * 8, &As[idx * 8]);
  }
  __syncthreads();

  // hoist A fragments (64 VGPRs)
  s16x8 afr[2][8];
#pragma unroll
  for (int mi = 0; mi < 2; ++mi) {
    int row = wy + mi * 16 + l16;
#pragma unroll
    for (int ki = 0; ki < 8; ++ki) {
      int cl = (ki * 4 + quad) ^ (row & 7);
      afr[mi][ki] = *(const s16x8*)&As[row * 256 + cl * 8];
    }
  }

  f32x4 outacc[2][2][2];  // [oc][mi][ni]
#pragma unroll
  for (int a = 0; a < 2; ++a)
#pragma unroll
    for (int b = 0; b < 2; ++b)
#pragma unroll
      for (int c = 0; c < 2; ++c) outacc[a][b][c] = (f32x4){0.f, 0.f, 0.f, 0.f};

  const int shift = (O == 128) ? 1 : 0;
  const int ntiles = O >> 2;   // (O*16)/64

  // per-lane B base: row (wx+ni*16+l16) within tile, k offset quad*8
  const u16* Bb = A.Bt + (size_t)(wx + l16) * 256 + quad * 8;

  for (int tl = 0; tl < ntiles; ++tl) {
    const int d = tl >> shift;
    const int oc = tl & shift;
    const u16* Bt0 = Bb + (size_t)(d * O + oc * 64) * 256;

    f32x4 acc[2][2];
#pragma unroll
    for (int a = 0; a < 2; ++a)
#pragma unroll
      for (int b = 0; b < 2; ++b) acc[a][b] = (f32x4){0.f, 0.f, 0.f, 0.f};

#pragma unroll
    for (int ki = 0; ki < 8; ++ki) {
      s16x8 bfr[2];
#pragma unroll
      for (int ni = 0; ni < 2; ++ni)
        bfr[ni] = *(const s16x8*)(Bt0 + (size_t)ni * 16 * 256 + ki * 32);
#pragma unroll
      for (int mi = 0; mi < 2; ++mi)
#pragma unroll
        for (int ni = 0; ni < 2; ++ni)
          acc[mi][ni] = __builtin_amdgcn_mfma_f32_16x16x32_bf16(afr[mi][ki], bfr[ni], acc[mi][ni], 0, 0, 0);
    }

    // fold d: outacc += ew[n,d]*acc
#pragma unroll
    for (int mi = 0; mi < 2; ++mi) {
      int nl = (wy + mi * 16 + quad * 4) >> 3;
      float s = ewS[nl][d];
#pragma unroll
      for (int ni = 0; ni < 2; ++ni)
#pragma unroll
        for (int r = 0; r < 4; ++r)
          outacc[oc][mi][ni][r] += s * acc[mi][ni][r];
    }
  }

  // epilogue: bias + activation + store from registers
#pragma unroll
  for (int oc = 0; oc <= shift; ++oc)
#pragma unroll
    for (int mi = 0; mi < 2; ++mi)
#pragma unroll
      for (int ni = 0; ni < 2; ++ni)
#pragma unroll
        for (int r = 0; r < 4; ++r) {
          int row = row0 + wy + mi * 16 + quad * 4 + r;
          int n = row >> 3, b = row & 7;
          int o = oc * 64 + wx + ni * 16 + l16;
          float pre = outacc[oc][mi][ni][r] + A.Bias[(size_t)mode * 1000 * O + n * O + o];
          if (is_gate) {
            float sg = 1.f / (1.f + __expf(-pre));
            if (o < 64) {
              float st = A.state[mode][(b * 1000 + n) * 64 + o];
              float zs = sg * st;
              A.ZSt[(size_t)mode * 524288 + (size_t)(b * 64 + o) * 1024 + n] = (u16)f2bf(zs);
              A.AgU[(size_t)mode * 2048000 + (size_t)row * 256 + 16 + o] = (u16)f2bf(zs);
            } else {
              A.Rb[(size_t)mode * 512000 + row * 64 + (o - 64)] = sg;
            }
          } else {
            float hc = tanhf(pre);
            float rr = A.Rb[(size_t)mode * 512000 + row * 64 + o];
            float st = A.state[mode][(b * 1000 + n) * 64 + o];
            A.out[(size_t)mode * 512000 + (b * 1000 + n) * 64 + o] = rr * st + (1.f - rr) * hc;
          }
        }
}

// ---------------------------------------------------------------------------
extern "C" void kernel_launch(void* const* d_in, const int* in_sizes, int n_in,
                              void* d_out, int out_size, void* d_ws, size_t ws_size,
                              hipStream_t stream) {
  const float* x[3]   = {(const float*)d_in[0], (const float*)d_in[1], (const float*)d_in[2]};
  const float* st[3]  = {(const float*)d_in[3], (const float*)d_in[4], (const float*)d_in[5]};
  const float* S[3]   = {(const float*)d_in[6], (const float*)d_in[7], (const float*)d_in[8]};
  const float* emb[3] = {(const float*)d_in[9], (const float*)d_in[10], (const float*)d_in[11]};
  const float* me = (const float*)d_in[12];
  const float* Wg = (const float*)d_in[13];
  const float* Bg = (const float*)d_in[14];
  const float* Wu = (const float*)d_in[15];
  const float* Bu = (const float*)d_in[16];
  float* out = (float*)d_out;

  float* BiG = (float*)d_ws;            // 3*1000*128
  float* BiU = BiG + 384000;            // 3*1000*64
  float* Rb  = BiU + 192000;            // 3*8000*64
  u16* S16 = (u16*)(Rb + 1536000);      // 3*1024*1024
  u16* Xt  = S16 + 3145728;             // 3*640*1024
  u16* T1t = Xt + 1966080;              // 3*640*1024
  u16* ZSt = T1t + 1966080;             // 3*512*1024
  u16* SZ1t= ZSt + 1572864;             // 3*512*1024
  u16* Ag  = SZ1t + 1572864;            // 3*8000*256
  u16* AgU = Ag + 6144000;              // 3*8000*256
  u16* BtG = AgU + 6144000;             // 2048*256
  u16* BtU = BtG + 524288;              // 1024*256

  {
    PrepArgs P;
    for (int m = 0; m < 3; ++m) { P.x[m] = x[m]; P.st[m] = st[m]; P.S[m] = S[m]; }
    P.S16 = S16; P.Xt = Xt; P.Ag = Ag; P.AgU = AgU; P.T1t = T1t; P.ZSt = ZSt; P.SZ1t = SZ1t;
    prep<<<32436, 256, 0, stream>>>(P);
  }
  bias_kernel<<<1500, 256, 0, stream>>>(emb[0], emb[1], emb[2], me, Bg, 128, BiG);
  bias_kernel<<<750, 256, 0, stream>>>(emb[0], emb[1], emb[2], me, Bu, 64, BiU);
  packW_kernel<<<3072, 256, 0, stream>>>(Wg, Wu, BtG, BtU);

  // cheb1: T1t = Xt @ S^T -> T1t + Ag[80..159] (+AgU x-part)
  {
    ChebArgs2 a;
    for (int m = 0; m < 3; ++m) {
      a.S16[m] = S16 + (size_t)m * 1048576; a.A[m] = Xt + (size_t)m * 655360;
      a.Res[m] = nullptr; a.Yt[m] = T1t + (size_t)m * 655360;
      a.AgA[m] = Ag + (size_t)m * 2048000; a.AgX[m] = AgU + (size_t)m * 2048000;
    }
    cheb_v5<<<dim3(8, 10, 3), 256, 0, stream>>>(a, 80, 80, 1.f, 0.f, 2 | 4);
  }
  // cheb2: T2t = 2*T1t @ S^T - Xt -> Ag[160..239] (+AgU x-part)
  {
    ChebArgs2 a;
    for (int m = 0; m < 3; ++m) {
      a.S16[m] = S16 + (size_t)m * 1048576; a.A[m] = T1t + (size_t)m * 655360;
      a.Res[m] = Xt + (size_t)m * 655360; a.Yt[m] = nullptr;
      a.AgA[m] = Ag + (size_t)m * 2048000; a.AgX[m] = AgU + (size_t)m * 2048000;
    }
    cheb_v5<<<dim3(8, 10, 3), 256, 0, stream>>>(a, 80, 160, 2.f, -1.f, 1 | 4);
  }
  // gate meta: reads Ag; writes ZSt + AgU[16..79] + Rb
  {
    Meta3Args a;
    a.Ag = Ag; a.Bt = BtG; a.me = me; a.Bias = BiG;
    a.ZSt = ZSt; a.AgU = AgU; a.Rb = Rb; a.out = out;
    for (int m = 0; m < 3; ++m) { a.emb[m] = emb[m]; a.state[m] = st[m]; }
    meta4<<<dim3(1, 125, 3), 256, 0, stream>>>(a, 1, 128);
  }
  // cheb3: SZ1t = ZSt @ S^T -> SZ1t + AgU[96..159]
  {
    ChebArgs2 a;
    for (int m = 0; m < 3; ++m) {
      a.S16[m] = S16 + (size_t)m * 1048576; a.A[m] = ZSt + (size_t)m * 524288;
      a.Res[m] = nullptr; a.Yt[m] = SZ1t + (size_t)m * 524288;
      a.AgA[m] = AgU + (size_t)m * 2048000; a.AgX[m] = nullptr;
    }
    cheb_v5<<<dim3(8, 8, 3), 256, 0, stream>>>(a, 64, 96, 1.f, 0.f, 2);
  }
  // cheb4: SZ2t = 2*SZ1t @ S^T - ZSt -> AgU[176..239]
  {
    ChebArgs2 a;
    for (int m = 0; m < 3; ++m) {
      a.S16[m] = S16 + (size_t)m * 1048576; a.A[m] = SZ1t + (size_t)m * 524288;
      a.Res[m] = ZSt + (size_t)m * 524288; a.Yt[m] = nullptr;
      a.AgA[m] = AgU + (size_t)m * 2048000; a.AgX[m] = nullptr;
    }
    cheb_v5<<<dim3(8, 8, 3), 256, 0, stream>>>(a, 64, 176, 2.f, -1.f, 1);
  }
  // update meta: reads AgU; writes out
  {
    Meta3Args a;
    a.Ag = AgU; a.Bt = BtU; a.me = me; a.Bias = BiU;
    a.ZSt = ZSt; a.AgU = AgU; a.Rb = Rb; a.out = out;
    for (int m = 0; m < 3; ++m) { a.emb[m] = emb[m]; a.state[m] = st[m]; }
    meta4<<<dim3(1, 125, 3), 256, 0, stream>>>(a, 0, 64);
  }
}

// Round 6
// 286.648 us; speedup vs baseline: 1.5070x; 1.5070x over previous
//
#include <hip/hip_runtime.h>
#include <math.h>

// ---------------------------------------------------------------------------
// HimNet multimode v6. B=8,N=1000,CIN=16,H=64,D=16,K=3,XIN=80,K*XIN=240,2H=128
//
// cheb GEMMs feature-major: T1t[f][n] = sum_k Xt[f][k]*S16[n][k].
//   cheb_v6: 64x64 tile, BK=64, DOUBLE-BUFFERED glds for A and B;
//   one barrier per K-iter; prefetch issued right after the barrier so the
//   next barrier's vmcnt drain waits on loads issued a full iter earlier.
// meta GEMM: A[8000x256] vs Btd d-major (Btd[(d*O+o)][k]=W[d,k,o]).
//   meta5: A frags loaded once global->regs; B double-buffered in LDS
//   (2x32KB), one barrier per 64-row B tile; register d-fold epilogue.
// ---------------------------------------------------------------------------

typedef __attribute__((ext_vector_type(8))) short s16x8;
typedef __attribute__((ext_vector_type(4))) float f32x4;
typedef unsigned short u16;
typedef unsigned int u32;
typedef unsigned long long u64;

__device__ __forceinline__ u32 f2bf(float f) {
  union { float f; u32 u; } v; v.f = f;
  return (v.u + 0x7FFFu + ((v.u >> 16) & 1u)) >> 16;  // RNE
}
__device__ __forceinline__ float bf2f(u16 h) {
  union { u32 u; float f; } v; v.u = (u32)h << 16; return v.f;
}
__device__ __forceinline__ void glds16(const u16* g, u16* l) {
  __builtin_amdgcn_global_load_lds(
      (const __attribute__((address_space(1))) void*)g,
      (__attribute__((address_space(3))) void*)l, 16, 0, 0);
}

// ---------------------------------------------------------------------------
// prep: S16[3][1024][1024], Xt[3][640][1024], Ag kc0 slots, AgU x-slots,
// K-pads, n-pad rows of T1t/ZSt/SZ1t.
// ---------------------------------------------------------------------------
#define E0 3145728
#define E1 1966080
#define E2 1920000
#define E3 384000
#define E4 384000
#define E5 384000
#define E6 119808
// total = 8303616 = 32436 * 256

struct PrepArgs {
  const float* x[3]; const float* st[3]; const float* S[3];
  u16 *S16, *Xt, *Ag, *AgU, *T1t, *ZSt, *SZ1t;
};

__global__ void prep(PrepArgs P) {
  long idx = (long)blockIdx.x * 256 + threadIdx.x;
  if (idx < E0) {  // S16 incl pads
    int m = (int)(idx >> 20); int rem = (int)(idx & 1048575);
    int n = rem >> 10, k = rem & 1023;
    float v = (n < 1000 && k < 1000) ? P.S[m][n * 1000 + k] : 0.f;
    P.S16[(size_t)m * 1048576 + rem] = (u16)f2bf(v); return;
  }
  idx -= E0;
  if (idx < E1) {  // Xt incl n-pads
    int m = (int)(idx / 655360); int rem = (int)(idx % 655360);
    int col = rem >> 10, nn = rem & 1023;
    int b = col / 80, c = col % 80;
    float v = 0.f;
    if (nn < 1000) v = (c < 16) ? P.x[m][(b * 1000 + nn) * 16 + c]
                                : P.st[m][(b * 1000 + nn) * 64 + c - 16];
    P.Xt[(size_t)m * 655360 + rem] = (u16)f2bf(v); return;
  }
  idx -= E1;
  if (idx < E2) {  // Ag kc0 (cols 0..79)
    int m = (int)(idx / 640000); int rem = (int)(idx % 640000);
    int r = rem / 80, c = rem % 80;
    int n = r >> 3, b = r & 7;
    float v = (c < 16) ? P.x[m][(b * 1000 + n) * 16 + c]
                       : P.st[m][(b * 1000 + n) * 64 + c - 16];
    P.Ag[(size_t)m * 2048000 + (size_t)r * 256 + c] = (u16)f2bf(v); return;
  }
  idx -= E2;
  if (idx < E3) {  // Ag K-pad 240..255
    int m = (int)(idx / 128000); int rem = (int)(idx % 128000);
    int r = rem / 16, c = 240 + rem % 16;
    P.Ag[(size_t)m * 2048000 + (size_t)r * 256 + c] = 0; return;
  }
  idx -= E3;
  if (idx < E4) {  // AgU kc0 x-part (cols 0..15)
    int m = (int)(idx / 128000); int rem = (int)(idx % 128000);
    int r = rem / 16, c = rem % 16;
    int n = r >> 3, b = r & 7;
    P.AgU[(size_t)m * 2048000 + (size_t)r * 256 + c] =
        (u16)f2bf(P.x[m][(b * 1000 + n) * 16 + c]); return;
  }
  idx -= E4;
  if (idx < E5) {  // AgU K-pad
    int m = (int)(idx / 128000); int rem = (int)(idx % 128000);
    int r = rem / 16, c = 240 + rem % 16;
    P.AgU[(size_t)m * 2048000 + (size_t)r * 256 + c] = 0; return;
  }
  idx -= E5;
  if (idx < E6) {  // n-pad rows (k=1000..1023) of T1t/ZSt/SZ1t
    int m = (int)(idx / 39936); int rem = (int)(idx % 39936);
    if (rem < 15360) { int col = rem / 24, j = rem % 24;
      P.T1t[(size_t)m * 655360 + col * 1024 + 1000 + j] = 0; }
    else if (rem < 27648) { int e = rem - 15360; int col = e / 24, j = e % 24;
      P.ZSt[(size_t)m * 524288 + col * 1024 + 1000 + j] = 0; }
    else { int e = rem - 27648; int col = e / 24, j = e % 24;
      P.SZ1t[(size_t)m * 524288 + col * 1024 + 1000 + j] = 0; }
    return;
  }
}

// ---------------------------------------------------------------------------
// bias: outB[mode][n*O+o] = sum_d emb[n,d]*me[mode,d]*Bp[d,o]
// ---------------------------------------------------------------------------
__global__ void bias_kernel(const float* __restrict__ e0, const float* __restrict__ e1,
                            const float* __restrict__ e2, const float* __restrict__ me,
                            const float* __restrict__ Bp, int O, float* __restrict__ outB) {
  int idx = blockIdx.x * blockDim.x + threadIdx.x;
  int total = 3 * 1000 * O;
  if (idx >= total) return;
  int mode = idx / (1000 * O);
  int rem  = idx % (1000 * O);
  int n = rem / O, o = rem % O;
  const float* emb = (mode == 0) ? e0 : (mode == 1) ? e1 : e2;
  float s = 0.f;
#pragma unroll
  for (int d = 0; d < 16; ++d)
    s += emb[n * 16 + d] * me[mode * 16 + d] * Bp[d * O + o];
  outB[idx] = s;
}

// ---------------------------------------------------------------------------
// packW (d-major): Bt[(d*O+o)][k] = bf16(W[d,k,o]) k<240, else 0.
// ---------------------------------------------------------------------------
__global__ void packW_kernel(const float* __restrict__ Wg, const float* __restrict__ Wu,
                             u16* __restrict__ BtG, u16* __restrict__ BtU) {
  int idx = blockIdx.x * blockDim.x + threadIdx.x;
  if (idx >= (2048 + 1024) * 256) return;
  if (idx < 2048 * 256) {
    int col = idx >> 8, k = idx & 255;
    int d = col >> 7, o = col & 127;
    BtG[idx] = (k < 240) ? (u16)f2bf(Wg[d * 30720 + k * 128 + o]) : (u16)0;
  } else {
    int i2 = idx - 2048 * 256;
    int col = i2 >> 8, k = i2 & 255;
    int d = col >> 6, o = col & 63;
    BtU[i2] = (k < 240) ? (u16)f2bf(Wu[d * 15360 + k * 64 + o]) : (u16)0;
  }
}

// ---------------------------------------------------------------------------
// cheb_v6: D[f][n] = alpha*sum_k A[f][k]*S16[n][k] (+beta*Res[f][n])
// 64x64 tile, BK=64, double-buffered glds; 1 barrier/iter.
// 4 waves 2x2 (32x32 each). flags: 1=hasRes, 2=hasY, 4=hasAgX
// ---------------------------------------------------------------------------
struct ChebArgs2 {
  const u16* S16[3]; const u16* A[3]; const u16* Res[3];
  u16* Yt[3]; u16* AgA[3]; u16* AgX[3];
};

__global__ __launch_bounds__(256, 4) void cheb_v6(ChebArgs2 g, int fdiv, int agbase,
                                                  float alpha, float beta, int flags) {
  const int mode = blockIdx.z;
  const u16* __restrict__ Ab = g.A[mode];
  const u16* __restrict__ Sb = g.S16[mode];

  __shared__ u16 As[2][64 * 64];   // 2 x 8KB
  __shared__ u16 Bs[2][64 * 64];   // 2 x 8KB

  const int t = threadIdx.x;
  const int row0 = blockIdx.y * 64, n0 = blockIdx.x * 64;
  const int lane = t & 63, wid = t >> 6;
  const int l16 = lane & 15, quad = lane >> 4;
  const int wy = (wid >> 1) * 32, wx = (wid & 1) * 32;

#define STAGE_CHEB(kk, bb)                                                      \
  {                                                                             \
    _Pragma("unroll")                                                           \
    for (int p = 0; p < 2; ++p) {                                               \
      int idx = p * 256 + t; int row = idx >> 3; int cs = (idx & 7) ^ (row & 7);\
      glds16(Ab + (size_t)(row0 + row) * 1024 + (kk) + cs * 8, &As[bb][idx * 8]);\
    }                                                                           \
    _Pragma("unroll")                                                           \
    for (int p = 0; p < 2; ++p) {                                               \
      int idx = p * 256 + t; int row = idx >> 3; int cs = (idx & 7) ^ (row & 7);\
      glds16(Sb + (size_t)(n0 + row) * 1024 + (kk) + cs * 8, &Bs[bb][idx * 8]); \
    }                                                                           \
  }

  f32x4 acc[2][2];
#pragma unroll
  for (int a = 0; a < 2; ++a)
#pragma unroll
    for (int b = 0; b < 2; ++b) acc[a][b] = (f32x4){0.f, 0.f, 0.f, 0.f};

  STAGE_CHEB(0, 0);

  for (int it = 0; it < 16; ++it) {
    __syncthreads();            // drains glds(it) (issued one full iter ago)
    if (it < 15) STAGE_CHEB((it + 1) * 64, (it + 1) & 1);
    const u16* Ac = As[it & 1];
    const u16* Bc = Bs[it & 1];
    s16x8 af[2][2], bf[2][2];
#pragma unroll
    for (int mi = 0; mi < 2; ++mi) {
      int row = wy + mi * 16 + l16;
#pragma unroll
      for (int ks = 0; ks < 2; ++ks) {
        int cl = (ks * 4 + quad) ^ (row & 7);
        af[mi][ks] = *(const s16x8*)&Ac[row * 64 + cl * 8];
      }
    }
#pragma unroll
    for (int ni = 0; ni < 2; ++ni) {
      int row = wx + ni * 16 + l16;
#pragma unroll
      for (int ks = 0; ks < 2; ++ks) {
        int cl = (ks * 4 + quad) ^ (row & 7);
        bf[ni][ks] = *(const s16x8*)&Bc[row * 64 + cl * 8];
      }
    }
#pragma unroll
    for (int ks = 0; ks < 2; ++ks)
#pragma unroll
      for (int mi = 0; mi < 2; ++mi)
#pragma unroll
        for (int ni = 0; ni < 2; ++ni)
          acc[mi][ni] = __builtin_amdgcn_mfma_f32_16x16x32_bf16(af[mi][ks], bf[ni][ks], acc[mi][ni], 0, 0, 0);
  }

#pragma unroll
  for (int mi = 0; mi < 2; ++mi) {
    int frow0 = row0 + wy + mi * 16 + quad * 4;
    int b = frow0 / fdiv, c0 = frow0 - b * fdiv;
#pragma unroll
    for (int ni = 0; ni < 2; ++ni) {
      int n = n0 + wx + ni * 16 + l16;
      if (n < 1000) {
        u16 pk[4];
#pragma unroll
        for (int r = 0; r < 4; ++r) {
          float v = alpha * acc[mi][ni][r];
          if (flags & 1) v += beta * bf2f(g.Res[mode][(size_t)(frow0 + r) * 1024 + n]);
          u16 h = (u16)f2bf(v);
          pk[r] = h;
          if (flags & 2) g.Yt[mode][(size_t)(frow0 + r) * 1024 + n] = h;
        }
        u64 pv = (u64)pk[0] | ((u64)pk[1] << 16) | ((u64)pk[2] << 32) | ((u64)pk[3] << 48);
        *(u64*)&g.AgA[mode][(size_t)(n * 8 + b) * 256 + agbase + c0] = pv;
        if ((flags & 4) && c0 < 16)
          *(u64*)&g.AgX[mode][(size_t)(n * 8 + b) * 256 + agbase + c0] = pv;
      }
    }
  }
}

// ---------------------------------------------------------------------------
// meta5: out[r,o] = act( sum_d ew[n,d]*(A[r,:].Btd[d*O+o,:]) + bias[n,o] )
// Block 64 rows; A frags loaded once global->regs (16 one-time loads);
// B double-buffered in LDS (2x32KB), 1 barrier per 64-row tile.
// 4 waves 2x2: wave = 32 rows x 32 cols. Register d-fold.
// ---------------------------------------------------------------------------
struct Meta3Args {
  const u16* Ag;        // [3][8000][256]
  const u16* Bt;        // [O*16][256] d-major
  const float* emb[3];
  const float* me;
  const float* Bias;    // [3][1000][O]
  const float* state[3];
  u16* ZSt;             // [3][512][1024]
  u16* AgU;             // [3][8000][256]
  float* Rb;            // [3][8000][64]
  float* out;
};

__global__ __launch_bounds__(256, 2) void meta5(Meta3Args A, int is_gate, int O) {
  const int mode = blockIdx.z;
  const int row0 = blockIdx.y * 64;
  const int n0 = row0 >> 3;

  __shared__ u16 Bs[2][64 * 256];   // 2 x 32KB
  __shared__ float ewS[8][17];

  const int t = threadIdx.x;
  if (t < 128) {
    int nl = t >> 4, d = t & 15;
    ewS[nl][d] = A.emb[mode][(n0 + nl) * 16 + d] * A.me[mode * 16 + d];
  }

  const int lane = t & 63, wid = t >> 6;
  const int l16 = lane & 15, quad = lane >> 4;
  const int wy = (wid >> 1) * 32, wx = (wid & 1) * 32;
  const u16* Agm = A.Ag + (size_t)mode * 2048000;

#define STAGE_B(brow0, bb)                                                      \
  {                                                                             \
    _Pragma("unroll")                                                           \
    for (int p = 0; p < 8; ++p) {                                               \
      int idx = p * 256 + t; int row = idx >> 5; int cs = (idx & 31) ^ (row & 7);\
      glds16(A.Bt + (size_t)((brow0) + row) * 256 + cs * 8, &Bs[bb][idx * 8]);  \
    }                                                                           \
  }

  const int shift = (O == 128) ? 1 : 0;
  const int ntiles = O >> 2;   // (O*16)/64: gate 32, update 16

  STAGE_B(0, 0);

  // A fragments: one-time global->regs (16B contiguous per frag)
  s16x8 afr[2][8];
#pragma unroll
  for (int mi = 0; mi < 2; ++mi) {
    const u16* arow = Agm + (size_t)(row0 + wy + mi * 16 + l16) * 256 + quad * 8;
#pragma unroll
    for (int ki = 0; ki < 8; ++ki)
      afr[mi][ki] = *(const s16x8*)(arow + ki * 32);
  }

  f32x4 outacc[2][2][2];  // [oc][mi][ni]
#pragma unroll
  for (int a = 0; a < 2; ++a)
#pragma unroll
    for (int b = 0; b < 2; ++b)
#pragma unroll
      for (int c = 0; c < 2; ++c) outacc[a][b][c] = (f32x4){0.f, 0.f, 0.f, 0.f};

  for (int tl = 0; tl < ntiles; ++tl) {
    __syncthreads();            // drains glds(tl) (issued one full tile ago)
    if (tl + 1 < ntiles) {
      int dn = (tl + 1) >> shift, ocn = (tl + 1) & shift;
      STAGE_B(dn * O + ocn * 64, (tl + 1) & 1);
    }
    const u16* Bc = Bs[tl & 1];
    const int d = tl >> shift, oc = tl & shift;

    f32x4 acc[2][2];
#pragma unroll
    for (int a = 0; a < 2; ++a)
#pragma unroll
      for (int b = 0; b < 2; ++b) acc[a][b] = (f32x4){0.f, 0.f, 0.f, 0.f};

#pragma unroll
    for (int ki = 0; ki < 8; ++ki) {
      s16x8 bfr[2];
#pragma unroll
      for (int ni = 0; ni < 2; ++ni) {
        int row = wx + ni * 16 + l16;
        int cl = (ki * 4 + quad) ^ (row & 7);
        bfr[ni] = *(const s16x8*)&Bc[row * 256 + cl * 8];
      }
#pragma unroll
      for (int mi = 0; mi < 2; ++mi)
#pragma unroll
        for (int ni = 0; ni < 2; ++ni)
          acc[mi][ni] = __builtin_amdgcn_mfma_f32_16x16x32_bf16(afr[mi][ki], bfr[ni], acc[mi][ni], 0, 0, 0);
    }

    // fold d: outacc += ew[n,d]*acc
#pragma unroll
    for (int mi = 0; mi < 2; ++mi) {
      int nl = (wy + mi * 16 + quad * 4) >> 3;
      float s = ewS[nl][d];
#pragma unroll
      for (int ni = 0; ni < 2; ++ni)
#pragma unroll
        for (int r = 0; r < 4; ++r)
          outacc[oc][mi][ni][r] += s * acc[mi][ni][r];
    }
  }

  // epilogue: bias + activation + store from registers
#pragma unroll
  for (int oc = 0; oc <= shift; ++oc)
#pragma unroll
    for (int mi = 0; mi < 2; ++mi)
#pragma unroll
      for (int ni = 0; ni < 2; ++ni)
#pragma unroll
        for (int r = 0; r < 4; ++r) {
          int row = row0 + wy + mi * 16 + quad * 4 + r;
          int n = row >> 3, b = row & 7;
          int o = oc * 64 + wx + ni * 16 + l16;
          float pre = outacc[oc][mi][ni][r] + A.Bias[(size_t)mode * 1000 * O + n * O + o];
          if (is_gate) {
            float sg = 1.f / (1.f + __expf(-pre));
            if (o < 64) {
              float st = A.state[mode][(b * 1000 + n) * 64 + o];
              float zs = sg * st;
              A.ZSt[(size_t)mode * 524288 + (size_t)(b * 64 + o) * 1024 + n] = (u16)f2bf(zs);
              A.AgU[(size_t)mode * 2048000 + (size_t)row * 256 + 16 + o] = (u16)f2bf(zs);
            } else {
              A.Rb[(size_t)mode * 512000 + row * 64 + (o - 64)] = sg;
            }
          } else {
            float hc = tanhf(pre);
            float rr = A.Rb[(size_t)mode * 512000 + row * 64 + o];
            float st = A.state[mode][(b * 1000 + n) * 64 + o];
            A.out[(size_t)mode * 512000 + (b * 1000 + n) * 64 + o] = rr * st + (1.f - rr) * hc;
          }
        }
}

// ---------------------------------------------------------------------------
extern "C" void kernel_launch(void* const* d_in, const int* in_sizes, int n_in,
                              void* d_out, int out_size, void* d_ws, size_t ws_size,
                              hipStream_t stream) {
  const float* x[3]   = {(const float*)d_in[0], (const float*)d_in[1], (const float*)d_in[2]};
  const float* st[3]  = {(const float*)d_in[3], (const float*)d_in[4], (const float*)d_in[5]};
  const float* S[3]   = {(const float*)d_in[6], (const float*)d_in[7], (const float*)d_in[8]};
  const float* emb[3] = {(const float*)d_in[9], (const float*)d_in[10], (const float*)d_in[11]};
  const float* me = (const float*)d_in[12];
  const float* Wg = (const float*)d_in[13];
  const float* Bg = (const float*)d_in[14];
  const float* Wu = (const float*)d_in[15];
  const float* Bu = (const float*)d_in[16];
  float* out = (float*)d_out;

  float* BiG = (float*)d_ws;            // 3*1000*128
  float* BiU = BiG + 384000;            // 3*1000*64
  float* Rb  = BiU + 192000;            // 3*8000*64
  u16* S16 = (u16*)(Rb + 1536000);      // 3*1024*1024
  u16* Xt  = S16 + 3145728;             // 3*640*1024
  u16* T1t = Xt + 1966080;              // 3*640*1024
  u16* ZSt = T1t + 1966080;             // 3*512*1024
  u16* SZ1t= ZSt + 1572864;             // 3*512*1024
  u16* Ag  = SZ1t + 1572864;            // 3*8000*256
  u16* AgU = Ag + 6144000;              // 3*8000*256
  u16* BtG = AgU + 6144000;             // 2048*256
  u16* BtU = BtG + 524288;              // 1024*256

  {
    PrepArgs P;
    for (int m = 0; m < 3; ++m) { P.x[m] = x[m]; P.st[m] = st[m]; P.S[m] = S[m]; }
    P.S16 = S16; P.Xt = Xt; P.Ag = Ag; P.AgU = AgU; P.T1t = T1t; P.ZSt = ZSt; P.SZ1t = SZ1t;
    prep<<<32436, 256, 0, stream>>>(P);
  }
  bias_kernel<<<1500, 256, 0, stream>>>(emb[0], emb[1], emb[2], me, Bg, 128, BiG);
  bias_kernel<<<750, 256, 0, stream>>>(emb[0], emb[1], emb[2], me, Bu, 64, BiU);
  packW_kernel<<<3072, 256, 0, stream>>>(Wg, Wu, BtG, BtU);

  // cheb1: T1t = Xt @ S^T -> T1t + Ag[80..159] (+AgU x-part)
  {
    ChebArgs2 a;
    for (int m = 0; m < 3; ++m) {
      a.S16[m] = S16 + (size_t)m * 1048576; a.A[m] = Xt + (size_t)m * 655360;
      a.Res[m] = nullptr; a.Yt[m] = T1t + (size_t)m * 655360;
      a.AgA[m] = Ag + (size_t)m * 2048000; a.AgX[m] = AgU + (size_t)m * 2048000;
    }
    cheb_v6<<<dim3(16, 10, 3), 256, 0, stream>>>(a, 80, 80, 1.f, 0.f, 2 | 4);
  }
  // cheb2: T2t = 2*T1t @ S^T - Xt -> Ag[160..239] (+AgU x-part)
  {
    ChebArgs2 a;
    for (int m = 0; m < 3; ++m) {
      a.S16[m] = S16 + (size_t)m * 1048576; a.A[m] = T1t + (size_t)m * 655360;
      a.Res[m] = Xt + (size_t)m * 655360; a.Yt[m] = nullptr;
      a.AgA[m] = Ag + (size_t)m * 2048000; a.AgX[m] = AgU + (size_t)m * 2048000;
    }
    cheb_v6<<<dim3(16, 10, 3), 256, 0, stream>>>(a, 80, 160, 2.f, -1.f, 1 | 4);
  }
  // gate meta: reads Ag; writes ZSt + AgU[16..79] + Rb
  {
    Meta3Args a;
    a.Ag = Ag; a.Bt = BtG; a.me = me; a.Bias = BiG;
    a.ZSt = ZSt; a.AgU = AgU; a.Rb = Rb; a.out = out;
    for (int m = 0; m < 3; ++m) { a.emb[m] = emb[m]; a.state[m] = st[m]; }
    meta5<<<dim3(1, 125, 3), 256, 0, stream>>>(a, 1, 128);
  }
  // cheb3: SZ1t = ZSt @ S^T -> SZ1t + AgU[96..159]
  {
    ChebArgs2 a;
    for (int m = 0; m < 3; ++m) {
      a.S16[m] = S16 + (size_t)m * 1048576; a.A[m] = ZSt + (size_t)m * 524288;
      a.Res[m] = nullptr; a.Yt[m] = SZ1t + (size_t)m * 524288;
      a.AgA[m] = AgU + (size_t)m * 2048000; a.AgX[m] = nullptr;
    }
    cheb_v6<<<dim3(16, 8, 3), 256, 0, stream>>>(a, 64, 96, 1.f, 0.f, 2);
  }
  // cheb4: SZ2t = 2*SZ1t @ S^T - ZSt -> AgU[176..239]
  {
    ChebArgs2 a;
    for (int m = 0; m < 3; ++m) {
      a.S16[m] = S16 + (size_t)m * 1048576; a.A[m] = SZ1t + (size_t)m * 524288;
      a.Res[m] = ZSt + (size_t)m * 524288; a.Yt[m] = nullptr;
      a.AgA[m] = AgU + (size_t)m * 2048000; a.AgX[m] = nullptr;
    }
    cheb_v6<<<dim3(16, 8, 3), 256, 0, stream>>>(a, 64, 176, 2.f, -1.f, 1);
  }
  // update meta: reads AgU; writes out
  {
    Meta3Args a;
    a.Ag = AgU; a.Bt = BtU; a.me = me; a.Bias = BiU;
    a.ZSt = ZSt; a.AgU = AgU; a.Rb = Rb; a.out = out;
    for (int m = 0; m < 3; ++m) { a.emb[m] = emb[m]; a.state[m] = st[m]; }
    meta5<<<dim3(1, 125, 3), 256, 0, stream>>>(a, 0, 64);
  }
}